// Round 13
// baseline (273.998 us; speedup 1.0000x reference)
//
#include <hip/hip_runtime.h>
#include <cstdint>
#include <cstddef>

// ---------------------------------------------------------------------------
// Fused GQA MHA: B=2 S=2048 D=2048, G=4 HPG=4 DH=128 (16 heads)
// gemm_proj (fp32-direct Q,K,V^T) | flash attn | gemm_out (fp32-direct WO)
// fp32->bf16 conversion fused into GEMM staging (no separate convert pass).
// ---------------------------------------------------------------------------

typedef __attribute__((ext_vector_type(8)))  __bf16 bf16x8;
typedef __attribute__((ext_vector_type(4)))  __bf16 bf16x4;
typedef __attribute__((ext_vector_type(4)))  float  f32x4;
typedef __attribute__((ext_vector_type(16))) float  f32x16;
typedef __attribute__((ext_vector_type(4)))  unsigned int u32x4;

#define GLD16(gp, lp) __builtin_amdgcn_global_load_lds(                         \
    (__attribute__((address_space(1))) void*)(size_t)(gp),                     \
    (__attribute__((address_space(3))) void*)(lp), 16, 0, 0)

#define PLSWAP(a, b) asm volatile("v_permlane32_swap_b32 %0, %1" : "+v"(a), "+v"(b))
#define EXP2F(x) __builtin_amdgcn_exp2f(x)

static __device__ __forceinline__ unsigned pack2bf(float a, float b) {
    unsigned short ua = __builtin_bit_cast(unsigned short, (__bf16)a);
    unsigned short ub = __builtin_bit_cast(unsigned short, (__bf16)b);
    return (unsigned)ua | ((unsigned)ub << 16);
}

// ---------------------------------------------------------------------------
// gemm32_body: C(256x128 tile) = A[M,K]*B[N,K]^T + bias. BK=32, 8 waves,
// triple-buffered LDS, counted vmcnt (T3/T4), chunk-XOR swizzle (T2).
// AF32/BF32: operand held fp32 in LDS, converted to bf16 AFTER lgkmcnt(0)
// (raw f32x4 pairs in regs so cvt doesn't force an early LDS wait).
// Loads/K-tile: NL = NLA+NLB (proj 4+2=6, out 2+2=4) -> vmcnt(NL) mid-loop.
// ---------------------------------------------------------------------------
template <int AF32, int BF32, int OUTF32>
static __device__ __forceinline__
void gemm32_body(const void* __restrict__ Ap, const void* __restrict__ Bp,
                 const float* __restrict__ bias, float* __restrict__ Cf,
                 __bf16* __restrict__ Cb, int N, int K, int m0, int n0,
                 int biasrow, char* As, char* Bs) {
    constexpr int EA = AF32 ? 4 : 2, EB = BF32 ? 4 : 2;
    constexpr int CPRA = 2 * EA, CPRB = 2 * EB;      // 16B chunks per 32-elem row
    constexpr int ATILE = 256 * 32 * EA, BTILE = 128 * 32 * EB;
    constexpr int NLA = 256 * CPRA / 512, NLB = 128 * CPRB / 512;
    constexpr int NL = NLA + NLB;
    const int tid = threadIdx.x, lane = tid & 63, wid = tid >> 6;
    const int g = lane >> 4, c = lane & 15;
    const int wr = wid >> 1, wc = wid & 1;
    const int nkt = K >> 5;
    const char* Abase = (const char*)Ap + (size_t)m0 * K * EA;
    const char* Bbase = (const char*)Bp + (size_t)n0 * K * EB;

    const f32x4 z = {0.f, 0.f, 0.f, 0.f};
    f32x4 acc[4][4];
#pragma unroll
    for (int i = 0; i < 4; ++i)
#pragma unroll
        for (int j = 0; j < 4; ++j) acc[i][j] = z;

    auto stage = [&](int b, int kt) {
        if (kt >= nkt) return;
        const char* sa = Abase + (size_t)kt * 32 * EA;
#pragma unroll
        for (int i = 0; i < NLA; ++i) {
            int ci = i * 512 + tid;
            int row = ci / CPRA, cp = ci % CPRA, chg = cp ^ (row & (CPRA - 1));
            GLD16(sa + (size_t)row * K * EA + chg * 16, As + b * ATILE + ci * 16);
        }
        const char* sb = Bbase + (size_t)kt * 32 * EB;
#pragma unroll
        for (int i = 0; i < NLB; ++i) {
            int ci = i * 512 + tid;
            int row = ci / CPRB, cp = ci % CPRB, chg = cp ^ (row & (CPRB - 1));
            GLD16(sb + (size_t)row * K * EB + chg * 16, Bs + b * BTILE + ci * 16);
        }
    };

    // prologue: tiles 0,1 in flight; retire tile 0 (tile 1 stays in flight)
    stage(0, 0);
    stage(1, 1);
    if constexpr (NL == 6) asm volatile("s_waitcnt vmcnt(6)" ::: "memory");
    else                   asm volatile("s_waitcnt vmcnt(4)" ::: "memory");
    __builtin_amdgcn_sched_barrier(0);
    __builtin_amdgcn_s_barrier();

    int bd = 0;
    for (int kt = 0; kt < nkt; ++kt) {
        const int bs = (bd >= 1) ? bd - 1 : 2;

        // ---- issue LDS reads of tile kt (raw; no use before lgkmcnt(0))
        f32x4 aLo[4], aHi[4], bLo[4], bHi[4];
        bf16x8 af[4], bfr[4];
#pragma unroll
        for (int mi = 0; mi < 4; ++mi) {
            int r = wr * 64 + mi * 16 + c;
            if constexpr (AF32) {
                const char* base = As + bd * ATILE + r * 128;
                aLo[mi] = *(const f32x4*)(base + (((2 * g)     ^ (r & 7)) * 16));
                aHi[mi] = *(const f32x4*)(base + (((2 * g + 1) ^ (r & 7)) * 16));
            } else {
                af[mi] = *(const bf16x8*)(As + bd * ATILE + r * 64 + ((g ^ (r & 3)) * 16));
            }
        }
#pragma unroll
        for (int ni = 0; ni < 4; ++ni) {
            int r = wc * 64 + ni * 16 + c;
            if constexpr (BF32) {
                const char* base = Bs + bd * BTILE + r * 128;
                bLo[ni] = *(const f32x4*)(base + (((2 * g)     ^ (r & 7)) * 16));
                bHi[ni] = *(const f32x4*)(base + (((2 * g + 1) ^ (r & 7)) * 16));
            } else {
                bfr[ni] = *(const bf16x8*)(Bs + bd * BTILE + r * 64 + ((g ^ (r & 3)) * 16));
            }
        }

        stage(bs, kt + 2);              // prefetch (never waited this iter)
        __builtin_amdgcn_s_barrier();
        asm volatile("s_waitcnt lgkmcnt(0)" ::: "memory");
        __builtin_amdgcn_sched_barrier(0);   // rule #18

        // ---- convert after the wait
        if constexpr (AF32) {
#pragma unroll
            for (int mi = 0; mi < 4; ++mi) {
                bf16x8 v;
                v[0] = (__bf16)aLo[mi][0]; v[1] = (__bf16)aLo[mi][1];
                v[2] = (__bf16)aLo[mi][2]; v[3] = (__bf16)aLo[mi][3];
                v[4] = (__bf16)aHi[mi][0]; v[5] = (__bf16)aHi[mi][1];
                v[6] = (__bf16)aHi[mi][2]; v[7] = (__bf16)aHi[mi][3];
                af[mi] = v;
            }
        }
        if constexpr (BF32) {
#pragma unroll
            for (int ni = 0; ni < 4; ++ni) {
                bf16x8 v;
                v[0] = (__bf16)bLo[ni][0]; v[1] = (__bf16)bLo[ni][1];
                v[2] = (__bf16)bLo[ni][2]; v[3] = (__bf16)bLo[ni][3];
                v[4] = (__bf16)bHi[ni][0]; v[5] = (__bf16)bHi[ni][1];
                v[6] = (__bf16)bHi[ni][2]; v[7] = (__bf16)bHi[ni][3];
                bfr[ni] = v;
            }
        }

        __builtin_amdgcn_s_setprio(1);
#pragma unroll
        for (int mi = 0; mi < 4; ++mi)
#pragma unroll
            for (int ni = 0; ni < 4; ++ni)
                acc[mi][ni] = __builtin_amdgcn_mfma_f32_16x16x32_bf16(
                    af[mi], bfr[ni], acc[mi][ni], 0, 0, 0);
        __builtin_amdgcn_s_setprio(0);

        if (kt >= nkt - 2) {
            asm volatile("s_waitcnt vmcnt(0)" ::: "memory");
        } else {
            if constexpr (NL == 6) asm volatile("s_waitcnt vmcnt(6)" ::: "memory");
            else                   asm volatile("s_waitcnt vmcnt(4)" ::: "memory");
        }
        __builtin_amdgcn_sched_barrier(0);
        __builtin_amdgcn_s_barrier();
        bd = (bd >= 2) ? 0 : bd + 1;
    }

    // epilogue: C/D layout col=lane&15, row=(lane>>4)*4+r  [m89]
#pragma unroll
    for (int mi = 0; mi < 4; ++mi) {
#pragma unroll
        for (int ni = 0; ni < 4; ++ni) {
            int col = n0 + wc * 64 + ni * 16 + c;
            float bvc = biasrow ? 0.f : bias[col];
#pragma unroll
            for (int r = 0; r < 4; ++r) {
                int row = m0 + wr * 64 + mi * 16 + g * 4 + r;
                float v = acc[mi][ni][r] + (biasrow ? bias[row] : bvc);
                if (OUTF32) Cf[(size_t)row * N + col] = v;
                else        Cb[(size_t)row * N + col] = (__bf16)v;
            }
        }
    }
}

// All projections, fp32 operands direct: [0,256)=Q, [256,320)=K, [320,384)=V^T
__global__ __launch_bounds__(512)
void gemm_proj(const float* __restrict__ q, const float* __restrict__ WQ,
               const float* __restrict__ bQ, __bf16* __restrict__ qp,
               const float* __restrict__ k, const float* __restrict__ WK,
               const float* __restrict__ bK, __bf16* __restrict__ kp,
               const float* __restrict__ WV, const float* __restrict__ v,
               const float* __restrict__ bV, __bf16* __restrict__ vpT) {
    __shared__ __align__(16) char As[3 * 32768];   // 96 KB fp32 A
    __shared__ __align__(16) char Bs[3 * 16384];   // 48 KB fp32 B
    const int bid = blockIdx.x;
    const int swz = (bid & 7) * 48 + (bid >> 3);   // 384 = 48*8, bijective
    if (swz < 256) {
        int bx = swz & 15, by = swz >> 4;
        gemm32_body<1, 1, 0>(q, WQ, bQ, nullptr, qp, 2048, 2048,
                             by * 256, bx * 128, 0, As, Bs);
    } else if (swz < 320) {
        int s = swz - 256;
        int bx = s & 3, by = s >> 2;
        gemm32_body<1, 1, 0>(k, WK, bK, nullptr, kp, 512, 2048,
                             by * 256, bx * 128, 0, As, Bs);
    } else {
        int s = swz - 320;
        int bx = s & 31, by = s >> 5;
        gemm32_body<1, 1, 0>(WV, v, bV, nullptr, vpT, 4096, 2048,
                             by * 256, bx * 128, 1, As, Bs);
    }
}

// O projection: A = ao (bf16), B = WO (fp32 direct), C fp32
__global__ __launch_bounds__(512)
void gemm_out(const __bf16* __restrict__ A, const float* __restrict__ WO,
              const float* __restrict__ bias, float* __restrict__ Cf) {
    __shared__ __align__(16) char As[3 * 16384];   // 48 KB bf16 A
    __shared__ __align__(16) char Bs[3 * 16384];   // 48 KB fp32 B
    const int bid = blockIdx.x;
    const int swz = (bid & 7) * 32 + (bid >> 3);
    int bx = swz & 15, by = swz >> 4;
    gemm32_body<0, 1, 1>(A, WO, bias, Cf, nullptr, 2048, 2048,
                         by * 256, bx * 128, 0, As, Bs);
}

// ---------------------------------------------------------------------------
// Flash attention (verbatim R12 — verified 115.5 us): 32x32x16 swapped-operand,
// XCD-exact placement, staggered start, KVBLK=32, triple-buffered, counted
// vmcnt(2) T15 double-pipeline.
// ---------------------------------------------------------------------------
__global__ __launch_bounds__(256)
void attn_kernel(const __bf16* __restrict__ Qw, const __bf16* __restrict__ Kw,
                 const __bf16* __restrict__ VTw, __bf16* __restrict__ Ow) {
    constexpr int S = 2048, DQ = 2048, DKV = 512, TOK = 4096;
    constexpr int nt = S / 32;
    const int bid = blockIdx.x;
    const int xcd = bid & 7, slot = bid >> 3;
    const int b = xcd >> 2, grp = xcd & 3;
    const int head = grp * 4 + (slot & 3);
    const int qblk = slot >> 2;
    const int t0 = slot & (nt - 1);
    const __bf16* Q   = Qw + (size_t)b * S * DQ + head * 128;
    const __bf16* Kp  = Kw + (size_t)b * S * DKV + grp * 128;
    const __bf16* VTp = VTw + (size_t)(grp * 128) * TOK + (size_t)b * S;
    __bf16* Op = Ow + (size_t)b * S * DQ + head * 128;

    __shared__ __bf16 Ks[3][32 * 128];
    __shared__ __bf16 Vs[3][128 * 32];

    const int tid = threadIdx.x, wid = tid >> 6, lane = tid & 63;
    const int ql = lane & 31, hi = lane >> 5;
    const int qrow = qblk * 128 + wid * 32 + ql;

    bf16x8 qf[8];
#pragma unroll
    for (int ks = 0; ks < 8; ++ks)
        qf[ks] = *(const bf16x8*)(Q + (size_t)qrow * DQ + ks * 16 + hi * 8);

    f32x16 o[4];
#pragma unroll
    for (int d = 0; d < 4; ++d)
#pragma unroll
        for (int r = 0; r < 16; ++r) o[d][r] = 0.f;
    float mprev = -1e30f, lsum = 0.f;
    constexpr float kexp = 0.08838834764831845f * 1.4426950408889634f;
    constexpr float THR = 8.0f / kexp;

    auto stage = [&](int t) {
        int buf = t % 3;
        int ta = (t0 + t) & (nt - 1);
#pragma unroll
        for (int i = 0; i < 2; ++i) {
            int ci = i * 256 + tid;
            int key = ci >> 4, ccl = ci & 15, ccg = ccl ^ (key & 15);
            GLD16(Kp + (size_t)(ta * 32 + key) * DKV + ccg * 8, &Ks[buf][ci * 8]);
        }
#pragma unroll
        for (int i = 0; i < 2; ++i) {
            int ci = i * 256 + tid;
            int dh = ci >> 2, cl = ci & 3, cg = cl ^ ((dh >> 1) & 3);
            GLD16(VTp + (size_t)dh * TOK + ta * 32 + cg * 8, &Vs[buf][ci * 8]);
        }
    };

    auto qkt = [&](int t, f32x16& scn) {
        const __bf16* kb = &Ks[t % 3][0];
#pragma unroll
        for (int r = 0; r < 16; ++r) scn[r] = 0.f;
        __builtin_amdgcn_s_setprio(1);
#pragma unroll
        for (int ks = 0; ks < 8; ++ks) {
            int chl = (ks * 2 + hi) ^ (ql & 15);
            bf16x8 kf = *(const bf16x8*)&kb[ql * 128 + chl * 8];
            scn = __builtin_amdgcn_mfma_f32_32x32x16_bf16(kf, qf[ks], scn, 0, 0, 0);
        }
        __builtin_amdgcn_s_setprio(0);
    };

    auto smpv = [&](int t, f32x16& sc) {
        const __bf16* vb = &Vs[t % 3][0];
        float mo = sc[0];
#pragma unroll
        for (int r = 1; r < 16; ++r) mo = fmaxf(mo, sc[r]);
        mo = fmaxf(mo, __shfl_xor(mo, 32, 64));
        if (!__all(mo - mprev <= THR)) {
            float mn = fmaxf(mprev, mo);
            float ef = EXP2F((mprev - mn) * kexp);
            lsum *= ef;
#pragma unroll
            for (int d = 0; d < 4; ++d)
#pragma unroll
                for (int r = 0; r < 16; ++r) o[d][r] *= ef;
            mprev = mn;
        }
        float mnk = mprev * kexp;
        float rs = 0.f;
#pragma unroll
        for (int r = 0; r < 16; ++r) {
            float p = EXP2F(__builtin_fmaf(sc[r], kexp, -mnk));
            sc[r] = p;
            rs += p;
        }
        rs += __shfl_xor(rs, 32, 64);
        lsum += rs;

        unsigned pk[4][2];
#pragma unroll
        for (int rg = 0; rg < 4; ++rg) {
            pk[rg][0] = pack2bf(sc[rg * 4 + 0], sc[rg * 4 + 1]);
            pk[rg][1] = pack2bf(sc[rg * 4 + 2], sc[rg * 4 + 3]);
        }

        __builtin_amdgcn_s_setprio(1);
#pragma unroll
        for (int e = 0; e < 2; ++e) {
            unsigned a0 = pk[2 * e][0], b0 = pk[2 * e + 1][0];
            unsigned a1 = pk[2 * e][1], b1 = pk[2 * e + 1][1];
            PLSWAP(a0, b0);
            PLSWAP(a1, b1);
            u32x4 fw = {a0, a1, b0, b1};
            bf16x8 pf = __builtin_bit_cast(bf16x8, fw);
#pragma unroll
            for (int dht = 0; dht < 4; ++dht) {
                int dh = dht * 32 + ql;
                int chl = (e * 2 + hi) ^ ((dh >> 1) & 3);
                bf16x8 vf = *(const bf16x8*)&vb[dh * 32 + chl * 8];
                o[dht] = __builtin_amdgcn_mfma_f32_32x32x16_bf16(vf, pf, o[dht], 0, 0, 0);
            }
        }
        __builtin_amdgcn_s_setprio(0);
    };

    f32x16 scA, scB;
    stage(0);
    stage(1);
    asm volatile("s_waitcnt vmcnt(2)" ::: "memory");
    asm volatile("s_barrier" ::: "memory");
    qkt(0, scA);

    for (int i = 0; i < nt; i += 2) {
        if (i + 2 < nt) stage(i + 2);
        qkt(i + 1, scB);
        smpv(i, scA);
        if (i + 2 < nt) asm volatile("s_waitcnt vmcnt(2)" ::: "memory");
        else            asm volatile("s_waitcnt vmcnt(0)" ::: "memory");
        asm volatile("s_barrier" ::: "memory");

        if (i + 3 < nt) stage(i + 3);
        if (i + 2 < nt) qkt(i + 2, scA);
        smpv(i + 1, scB);
        if (i + 3 < nt) asm volatile("s_waitcnt vmcnt(2)" ::: "memory");
        else            asm volatile("s_waitcnt vmcnt(0)" ::: "memory");
        asm volatile("s_barrier" ::: "memory");
    }

    float inv = 1.0f / lsum;
#pragma unroll
    for (int dht = 0; dht < 4; ++dht)
#pragma unroll
        for (int rg = 0; rg < 4; ++rg) {
            bf16x4 wv;
#pragma unroll
            for (int j = 0; j < 4; ++j) wv[j] = (__bf16)(o[dht][rg * 4 + j] * inv);
            int dh0 = dht * 32 + rg * 8 + hi * 4;
            *(bf16x4*)(Op + (size_t)qrow * DQ + dh0) = wv;
        }
}

// ---------------------------------------------------------------------------
extern "C" void kernel_launch(void* const* d_in, const int* in_sizes, int n_in,
                              void* d_out, int out_size, void* d_ws, size_t ws_size,
                              hipStream_t stream) {
    (void)in_sizes; (void)n_in; (void)out_size; (void)ws_size;
    const float* query = (const float*)d_in[0];
    const float* key   = (const float*)d_in[1];
    const float* value = (const float*)d_in[2];
    const float* WQ = (const float*)d_in[3];
    const float* bQ = (const float*)d_in[4];
    const float* WK = (const float*)d_in[5];
    const float* bK = (const float*)d_in[6];
    const float* WV = (const float*)d_in[7];
    const float* bV = (const float*)d_in[8];
    const float* WO = (const float*)d_in[9];
    const float* bO = (const float*)d_in[10];
    float* out = (float*)d_out;

    __bf16* w = (__bf16*)d_ws;
    __bf16* qp  = w; w += (size_t)4096 * 2048;  // Q proj [tok, 16*128]
    __bf16* kp  = w; w += (size_t)4096 * 512;   // K proj [tok, 4*128]
    __bf16* vpT = w; w += (size_t)512 * 4096;   // V proj transposed [4*128, tok]
    __bf16* ao  = w; w += (size_t)4096 * 2048;  // attention output

    // all projections (Q + K + V^T), fp32 operands direct, one dispatch
    gemm_proj<<<384, 512, 0, stream>>>(query, WQ, bQ, qp,
                                       key, WK, bK, kp,
                                       WV, value, bV, vpT);

    attn_kernel<<<512, 256, 0, stream>>>(qp, kp, vpT, ao);

    gemm_out<<<256, 512, 0, stream>>>(ao, WO, bO, out);
}

// Round 14
// 245.805 us; speedup vs baseline: 1.1147x; 1.1147x over previous
//
#include <hip/hip_runtime.h>
#include <cstdint>
#include <cstddef>

// ---------------------------------------------------------------------------
// Fused GQA MHA: B=2 S=2048 D=2048, G=4 HPG=4 DH=128 (16 heads)
// fused fp32->bf16 | gemm_proj (Q,K,V^T one dispatch) | flash attn | O proj
// (R12 configuration — verified 246.5 us. R13's in-GEMM fp32 staging reverted:
//  fp32 LDS rows are 128 B = exact 32-bank wrap -> unfixable read conflicts.)
// ---------------------------------------------------------------------------

typedef __attribute__((ext_vector_type(8)))  __bf16 bf16x8;
typedef __attribute__((ext_vector_type(4)))  __bf16 bf16x4;
typedef __attribute__((ext_vector_type(4)))  float  f32x4;
typedef __attribute__((ext_vector_type(16))) float  f32x16;
typedef __attribute__((ext_vector_type(4)))  unsigned int u32x4;

#define GLD16(gp, lp) __builtin_amdgcn_global_load_lds(                         \
    (__attribute__((address_space(1))) void*)(size_t)(gp),                     \
    (__attribute__((address_space(3))) void*)(lp), 16, 0, 0)

#define PLSWAP(a, b) asm volatile("v_permlane32_swap_b32 %0, %1" : "+v"(a), "+v"(b))
#define EXP2F(x) __builtin_amdgcn_exp2f(x)

static __device__ __forceinline__ unsigned pack2bf(float a, float b) {
    unsigned short ua = __builtin_bit_cast(unsigned short, (__bf16)a);
    unsigned short ub = __builtin_bit_cast(unsigned short, (__bf16)b);
    return (unsigned)ua | ((unsigned)ub << 16);
}

// ---------------------------------------------------------------------------
// Fused fp32->bf16 for all 7 tensors in one launch
// ---------------------------------------------------------------------------
struct F2BArgs {
    const float* src[7];
    __bf16* dst[7];
    long beg[8];
};
__global__ void f2b_multi(F2BArgs a) {
    const long total = a.beg[7];
    const long stride = (long)gridDim.x * blockDim.x;
    for (long i = (long)blockIdx.x * blockDim.x + threadIdx.x; i < total; i += stride) {
        int s = 0;
#pragma unroll
        for (int j = 1; j < 7; ++j) s += (i >= a.beg[j]);
        long off = i - a.beg[s];
        const float4* p = (const float4*)(a.src[s] + off * 8);
        float4 x = p[0], y = p[1];
        bf16x8 r;
        r[0] = (__bf16)x.x; r[1] = (__bf16)x.y; r[2] = (__bf16)x.z; r[3] = (__bf16)x.w;
        r[4] = (__bf16)y.x; r[5] = (__bf16)y.y; r[6] = (__bf16)y.z; r[7] = (__bf16)y.w;
        *(bf16x8*)(a.dst[s] + off * 8) = r;
    }
}

// ---------------------------------------------------------------------------
// gemm256 body (R6-verified): 256x128 tile, BK=64, 8 waves, triple-buffered,
// counted vmcnt(6)
// ---------------------------------------------------------------------------
template <int OUTF32>
static __device__ __forceinline__
void gemm256_body(const __bf16* __restrict__ A, const __bf16* __restrict__ Bm,
                  const float* __restrict__ bias, float* __restrict__ Cf,
                  __bf16* __restrict__ Cb, int N, int K, int m0, int n0,
                  int biasrow, __bf16* As, __bf16* Bs) {
    const int tid = threadIdx.x, lane = tid & 63, wid = tid >> 6;
    const int g = lane >> 4, c = lane & 15;
    const int wr = wid >> 1, wc = wid & 1;
    const int nkt = K >> 6;

    const f32x4 z = {0.f, 0.f, 0.f, 0.f};
    f32x4 acc[4][4];
#pragma unroll
    for (int i = 0; i < 4; ++i)
#pragma unroll
        for (int j = 0; j < 4; ++j) acc[i][j] = z;

    auto stageA = [&](int b, int kt, int h) {
        if (kt >= nkt) return;
        const __bf16* src = A + (size_t)m0 * K + (size_t)kt * 64;
#pragma unroll
        for (int i = 0; i < 2; ++i) {
            int ci = h * 1024 + i * 512 + tid;
            int row = ci >> 3, chg = (ci & 7) ^ (row & 7);
            GLD16(src + (size_t)row * K + chg * 8, &As[b * 16384 + ci * 8]);
        }
    };
    auto stageB = [&](int b, int kt) {
        if (kt >= nkt) return;
        const __bf16* src = Bm + (size_t)n0 * K + (size_t)kt * 64;
#pragma unroll
        for (int i = 0; i < 2; ++i) {
            int ci = i * 512 + tid;
            int row = ci >> 3, chg = (ci & 7) ^ (row & 7);
            GLD16(src + (size_t)row * K + chg * 8, &Bs[b * 8192 + ci * 8]);
        }
    };

    stageA(0, 0, 0); stageA(0, 0, 1); stageB(0, 0);
    stageA(1, 1, 0); stageA(1, 1, 1); stageB(1, 1);
    asm volatile("s_waitcnt vmcnt(6)" ::: "memory");
    __builtin_amdgcn_sched_barrier(0);
    __builtin_amdgcn_s_barrier();

    int bd = 0;
    for (int kt = 0; kt < nkt; ++kt) {
        const int bs = (bd >= 1) ? bd - 1 : 2;
        bf16x8 af[4], bfr[4];
#pragma unroll
        for (int ph = 0; ph < 2; ++ph) {
#pragma unroll
            for (int mi = 0; mi < 4; ++mi) {
                int row = wr * 64 + mi * 16 + c;
                int ch = (ph * 4 + g) ^ (c & 7);
                af[mi] = *(const bf16x8*)&As[bd * 16384 + row * 64 + ch * 8];
            }
#pragma unroll
            for (int ni = 0; ni < 4; ++ni) {
                int row = wc * 64 + ni * 16 + c;
                int ch = (ph * 4 + g) ^ (c & 7);
                bfr[ni] = *(const bf16x8*)&Bs[bd * 8192 + row * 64 + ch * 8];
            }
            if (ph == 0) {
                stageA(bs, kt + 2, 0);
            } else {
                stageA(bs, kt + 2, 1);
                stageB(bs, kt + 2);
            }
            __builtin_amdgcn_s_barrier();
            asm volatile("s_waitcnt lgkmcnt(0)" ::: "memory");
            __builtin_amdgcn_sched_barrier(0);
            __builtin_amdgcn_s_setprio(1);
#pragma unroll
            for (int mi = 0; mi < 4; ++mi)
#pragma unroll
                for (int ni = 0; ni < 4; ++ni)
                    acc[mi][ni] = __builtin_amdgcn_mfma_f32_16x16x32_bf16(
                        af[mi], bfr[ni], acc[mi][ni], 0, 0, 0);
            __builtin_amdgcn_s_setprio(0);
            if (ph == 1) {
                if (kt >= nkt - 2) asm volatile("s_waitcnt vmcnt(0)" ::: "memory");
                else               asm volatile("s_waitcnt vmcnt(6)" ::: "memory");
                __builtin_amdgcn_sched_barrier(0);
            }
            __builtin_amdgcn_s_barrier();
        }
        bd = (bd >= 2) ? 0 : bd + 1;
    }

#pragma unroll
    for (int mi = 0; mi < 4; ++mi) {
#pragma unroll
        for (int ni = 0; ni < 4; ++ni) {
            int col = n0 + wc * 64 + ni * 16 + c;
            float bvc = biasrow ? 0.f : bias[col];
#pragma unroll
            for (int r = 0; r < 4; ++r) {
                int row = m0 + wr * 64 + mi * 16 + g * 4 + r;
                float v = acc[mi][ni][r] + (biasrow ? bias[row] : bvc);
                if (OUTF32) Cf[(size_t)row * N + col] = v;
                else        Cb[(size_t)row * N + col] = (__bf16)v;
            }
        }
    }
}

// All projections in one dispatch: blocks [0,256)=Q, [256,320)=K, [320,384)=V^T
__global__ __launch_bounds__(512)
void gemm_proj(const __bf16* __restrict__ qb, const __bf16* __restrict__ wqb,
               const float* __restrict__ bQ, __bf16* __restrict__ qp,
               const __bf16* __restrict__ kb, const __bf16* __restrict__ wkb,
               const float* __restrict__ bK, __bf16* __restrict__ kp,
               const __bf16* __restrict__ wvb, const __bf16* __restrict__ vb,
               const float* __restrict__ bV, __bf16* __restrict__ vpT) {
    __shared__ __bf16 As[3 * 256 * 64];
    __shared__ __bf16 Bs[3 * 128 * 64];
    const int bid = blockIdx.x;
    const int swz = (bid & 7) * 48 + (bid >> 3);   // 384 = 48*8, bijective
    if (swz < 256) {
        int bx = swz & 15, by = swz >> 4;
        gemm256_body<0>(qb, wqb, bQ, nullptr, qp, 2048, 2048,
                        by * 256, bx * 128, 0, As, Bs);
    } else if (swz < 320) {
        int s = swz - 256;
        int bx = s & 3, by = s >> 2;
        gemm256_body<0>(kb, wkb, bK, nullptr, kp, 512, 2048,
                        by * 256, bx * 128, 0, As, Bs);
    } else {
        int s = swz - 320;
        int bx = s & 31, by = s >> 5;
        gemm256_body<0>(wvb, vb, bV, nullptr, vpT, 4096, 2048,
                        by * 256, bx * 128, 1, As, Bs);
    }
}

// O projection (fp32 out), 256 blocks
__global__ __launch_bounds__(512)
void gemm_out(const __bf16* __restrict__ A, const __bf16* __restrict__ Bm,
              const float* __restrict__ bias, float* __restrict__ Cf) {
    __shared__ __bf16 As[3 * 256 * 64];
    __shared__ __bf16 Bs[3 * 128 * 64];
    const int bid = blockIdx.x;
    const int swz = (bid & 7) * 32 + (bid >> 3);
    int bx = swz & 15, by = swz >> 4;
    gemm256_body<1>(A, Bm, bias, Cf, nullptr, 2048, 2048,
                    by * 256, bx * 128, 0, As, Bs);
}

// ---------------------------------------------------------------------------
// Flash attention (verbatim R12 — verified 115.5 us): 32x32x16 swapped-operand,
// XCD-exact placement, staggered start, KVBLK=32, triple-buffered, counted
// vmcnt(2) T15 double-pipeline.
// ---------------------------------------------------------------------------
__global__ __launch_bounds__(256)
void attn_kernel(const __bf16* __restrict__ Qw, const __bf16* __restrict__ Kw,
                 const __bf16* __restrict__ VTw, __bf16* __restrict__ Ow) {
    constexpr int S = 2048, DQ = 2048, DKV = 512, TOK = 4096;
    constexpr int nt = S / 32;
    const int bid = blockIdx.x;
    const int xcd = bid & 7, slot = bid >> 3;
    const int b = xcd >> 2, grp = xcd & 3;
    const int head = grp * 4 + (slot & 3);
    const int qblk = slot >> 2;
    const int t0 = slot & (nt - 1);
    const __bf16* Q   = Qw + (size_t)b * S * DQ + head * 128;
    const __bf16* Kp  = Kw + (size_t)b * S * DKV + grp * 128;
    const __bf16* VTp = VTw + (size_t)(grp * 128) * TOK + (size_t)b * S;
    __bf16* Op = Ow + (size_t)b * S * DQ + head * 128;

    __shared__ __bf16 Ks[3][32 * 128];
    __shared__ __bf16 Vs[3][128 * 32];

    const int tid = threadIdx.x, wid = tid >> 6, lane = tid & 63;
    const int ql = lane & 31, hi = lane >> 5;
    const int qrow = qblk * 128 + wid * 32 + ql;

    bf16x8 qf[8];
#pragma unroll
    for (int ks = 0; ks < 8; ++ks)
        qf[ks] = *(const bf16x8*)(Q + (size_t)qrow * DQ + ks * 16 + hi * 8);

    f32x16 o[4];
#pragma unroll
    for (int d = 0; d < 4; ++d)
#pragma unroll
        for (int r = 0; r < 16; ++r) o[d][r] = 0.f;
    float mprev = -1e30f, lsum = 0.f;
    constexpr float kexp = 0.08838834764831845f * 1.4426950408889634f;
    constexpr float THR = 8.0f / kexp;

    auto stage = [&](int t) {
        int buf = t % 3;
        int ta = (t0 + t) & (nt - 1);
#pragma unroll
        for (int i = 0; i < 2; ++i) {
            int ci = i * 256 + tid;
            int key = ci >> 4, ccl = ci & 15, ccg = ccl ^ (key & 15);
            GLD16(Kp + (size_t)(ta * 32 + key) * DKV + ccg * 8, &Ks[buf][ci * 8]);
        }
#pragma unroll
        for (int i = 0; i < 2; ++i) {
            int ci = i * 256 + tid;
            int dh = ci >> 2, cl = ci & 3, cg = cl ^ ((dh >> 1) & 3);
            GLD16(VTp + (size_t)dh * TOK + ta * 32 + cg * 8, &Vs[buf][ci * 8]);
        }
    };

    auto qkt = [&](int t, f32x16& scn) {
        const __bf16* kb = &Ks[t % 3][0];
#pragma unroll
        for (int r = 0; r < 16; ++r) scn[r] = 0.f;
        __builtin_amdgcn_s_setprio(1);
#pragma unroll
        for (int ks = 0; ks < 8; ++ks) {
            int chl = (ks * 2 + hi) ^ (ql & 15);
            bf16x8 kf = *(const bf16x8*)&kb[ql * 128 + chl * 8];
            scn = __builtin_amdgcn_mfma_f32_32x32x16_bf16(kf, qf[ks], scn, 0, 0, 0);
        }
        __builtin_amdgcn_s_setprio(0);
    };

    auto smpv = [&](int t, f32x16& sc) {
        const __bf16* vb = &Vs[t % 3][0];
        float mo = sc[0];
#pragma unroll
        for (int r = 1; r < 16; ++r) mo = fmaxf(mo, sc[r]);
        mo = fmaxf(mo, __shfl_xor(mo, 32, 64));
        if (!__all(mo - mprev <= THR)) {
            float mn = fmaxf(mprev, mo);
            float ef = EXP2F((mprev - mn) * kexp);
            lsum *= ef;
#pragma unroll
            for (int d = 0; d < 4; ++d)
#pragma unroll
                for (int r = 0; r < 16; ++r) o[d][r] *= ef;
            mprev = mn;
        }
        float mnk = mprev * kexp;
        float rs = 0.f;
#pragma unroll
        for (int r = 0; r < 16; ++r) {
            float p = EXP2F(__builtin_fmaf(sc[r], kexp, -mnk));
            sc[r] = p;
            rs += p;
        }
        rs += __shfl_xor(rs, 32, 64);
        lsum += rs;

        unsigned pk[4][2];
#pragma unroll
        for (int rg = 0; rg < 4; ++rg) {
            pk[rg][0] = pack2bf(sc[rg * 4 + 0], sc[rg * 4 + 1]);
            pk[rg][1] = pack2bf(sc[rg * 4 + 2], sc[rg * 4 + 3]);
        }

        __builtin_amdgcn_s_setprio(1);
#pragma unroll
        for (int e = 0; e < 2; ++e) {
            unsigned a0 = pk[2 * e][0], b0 = pk[2 * e + 1][0];
            unsigned a1 = pk[2 * e][1], b1 = pk[2 * e + 1][1];
            PLSWAP(a0, b0);
            PLSWAP(a1, b1);
            u32x4 fw = {a0, a1, b0, b1};
            bf16x8 pf = __builtin_bit_cast(bf16x8, fw);
#pragma unroll
            for (int dht = 0; dht < 4; ++dht) {
                int dh = dht * 32 + ql;
                int chl = (e * 2 + hi) ^ ((dh >> 1) & 3);
                bf16x8 vf = *(const bf16x8*)&vb[dh * 32 + chl * 8];
                o[dht] = __builtin_amdgcn_mfma_f32_32x32x16_bf16(vf, pf, o[dht], 0, 0, 0);
            }
        }
        __builtin_amdgcn_s_setprio(0);
    };

    f32x16 scA, scB;
    stage(0);
    stage(1);
    asm volatile("s_waitcnt vmcnt(2)" ::: "memory");
    asm volatile("s_barrier" ::: "memory");
    qkt(0, scA);

    for (int i = 0; i < nt; i += 2) {
        if (i + 2 < nt) stage(i + 2);
        qkt(i + 1, scB);
        smpv(i, scA);
        if (i + 2 < nt) asm volatile("s_waitcnt vmcnt(2)" ::: "memory");
        else            asm volatile("s_waitcnt vmcnt(0)" ::: "memory");
        asm volatile("s_barrier" ::: "memory");

        if (i + 3 < nt) stage(i + 3);
        if (i + 2 < nt) qkt(i + 2, scA);
        smpv(i + 1, scB);
        if (i + 3 < nt) asm volatile("s_waitcnt vmcnt(2)" ::: "memory");
        else            asm volatile("s_waitcnt vmcnt(0)" ::: "memory");
        asm volatile("s_barrier" ::: "memory");
    }

    float inv = 1.0f / lsum;
#pragma unroll
    for (int dht = 0; dht < 4; ++dht)
#pragma unroll
        for (int rg = 0; rg < 4; ++rg) {
            bf16x4 wv;
#pragma unroll
            for (int j = 0; j < 4; ++j) wv[j] = (__bf16)(o[dht][rg * 4 + j] * inv);
            int dh0 = dht * 32 + rg * 8 + hi * 4;
            *(bf16x4*)(Op + (size_t)qrow * DQ + dh0) = wv;
        }
}

// ---------------------------------------------------------------------------
extern "C" void kernel_launch(void* const* d_in, const int* in_sizes, int n_in,
                              void* d_out, int out_size, void* d_ws, size_t ws_size,
                              hipStream_t stream) {
    (void)in_sizes; (void)n_in; (void)out_size; (void)ws_size;
    const float* query = (const float*)d_in[0];
    const float* key   = (const float*)d_in[1];
    const float* value = (const float*)d_in[2];
    const float* WQ = (const float*)d_in[3];
    const float* bQ = (const float*)d_in[4];
    const float* WK = (const float*)d_in[5];
    const float* bK = (const float*)d_in[6];
    const float* WV = (const float*)d_in[7];
    const float* bV = (const float*)d_in[8];
    const float* WO = (const float*)d_in[9];
    const float* bO = (const float*)d_in[10];
    float* out = (float*)d_out;

    __bf16* w = (__bf16*)d_ws;
    __bf16* qb  = w; w += (size_t)4096 * 2048;
    __bf16* kb  = w; w += (size_t)4096 * 2048;
    __bf16* vb  = w; w += (size_t)4096 * 2048;
    __bf16* wqb = w; w += (size_t)2048 * 2048;
    __bf16* wkb = w; w += (size_t)512 * 2048;
    __bf16* wvb = w; w += (size_t)512 * 2048;
    __bf16* wob = w; w += (size_t)2048 * 2048;
    __bf16* qp  = w; w += (size_t)4096 * 2048;
    __bf16* kp  = w; w += (size_t)4096 * 512;
    __bf16* vpT = w; w += (size_t)512 * 4096;
    __bf16* ao  = w; w += (size_t)4096 * 2048;

    F2BArgs fa;
    fa.src[0] = query; fa.dst[0] = qb;
    fa.src[1] = key;   fa.dst[1] = kb;
    fa.src[2] = value; fa.dst[2] = vb;
    fa.src[3] = WQ;    fa.dst[3] = wqb;
    fa.src[4] = WK;    fa.dst[4] = wkb;
    fa.src[5] = WV;    fa.dst[5] = wvb;
    fa.src[6] = WO;    fa.dst[6] = wob;
    const long n8s[7] = {1048576, 1048576, 1048576, 524288, 131072, 131072, 524288};
    long acc = 0;
    for (int i = 0; i < 7; ++i) { fa.beg[i] = acc; acc += n8s[i]; }
    fa.beg[7] = acc;
    f2b_multi<<<2048, 256, 0, stream>>>(fa);

    gemm_proj<<<384, 512, 0, stream>>>(qb, wqb, bQ, qp,
                                       kb, wkb, bK, kp,
                                       wvb, vb, bV, vpT);

    attn_kernel<<<512, 256, 0, stream>>>(qp, kp, vpT, ao);

    gemm_out<<<256, 512, 0, stream>>>(ao, wob, bO, out);
}